// Round 1
// 252.821 us; speedup vs baseline: 1.0003x; 1.0003x over previous
//
#include <hip/hip_runtime.h>

#define N_NODES 100000
#define N_EDGES 1000000
#define D_IN    256
#define D_OUT   64

// bucket decomposition: 256 nodes per bucket
#define BKT_SHIFT   8
#define NODES_PER_B 256
#define N_BKT       391            // ceil(100000 / 256)
#define BKT_CAP     3072           // mean 2558, sigma ~51 -> +10 sigma slack
#define EPB         8192           // edges per binning block
#define BIN_BLOCKS  123            // ceil(1e6 / 8192)
#define GEMM_BLOCKS 782            // 3128 waves, 2 tiles/wave, 6250 tiles exact
#define NUM_TILES   6250           // 100000 / 16 exactly

// gCursor padding: one counter per 128-B line. 391 counters packed into
// ~25 lines caused 48K cross-XCD atomic-RMWs-with-return to serialize on
// ~12-25 lines (~2K same-line RMWs x ~30ns = the ~55us bin-path stall seen
// as MfmaUtil 1.5% / Occupancy 13%). Padded: 123 RMWs per line, parallel
// across 391 lines.
#define CUR_STRIDE  32

typedef __attribute__((ext_vector_type(8))) short short8;
typedef __attribute__((ext_vector_type(4))) float f32x4;

__device__ __forceinline__ unsigned short f2bf(float f) {
    unsigned int u = __float_as_uint(f);
    u = (u + 0x7fffu + ((u >> 16) & 1u)) >> 16;
    return (unsigned short)u;
}

// MFMA + store for one 16-row tile; B read from LDS per use (keeps VGPRs for
// the A-load pipeline). wT pad = 272 shorts (544 B = 8 banks offset/row ->
// 4-way b128 aliasing instead of 8-way at 264).
__device__ __forceinline__ void mfma_store_tile(
    const short8 afrag[8], const unsigned short wT[64][272],
    unsigned short* __restrict__ hiddenBf, int r0, int n16, int quad)
{
    f32x4 acc[4] = {{0.f,0.f,0.f,0.f},{0.f,0.f,0.f,0.f},
                    {0.f,0.f,0.f,0.f},{0.f,0.f,0.f,0.f}};
#pragma unroll
    for (int ct = 0; ct < 4; ++ct) {
#pragma unroll
        for (int kk = 0; kk < 8; ++kk) {
            short8 b = *(const short8*)&wT[ct * 16 + n16][kk * 32 + quad * 8];
            acc[ct] = __builtin_amdgcn_mfma_f32_16x16x32_bf16(
                afrag[kk], b, acc[ct], 0, 0, 0);
        }
    }
    // C/D layout: col = lane&15, row = quad*4 + reg  [m89-verified]
#pragma unroll
    for (int ct = 0; ct < 4; ++ct)
#pragma unroll
        for (int reg = 0; reg < 4; ++reg)
            hiddenBf[(size_t)(r0 + quad * 4 + reg) * D_OUT + ct * 16 + n16]
                = f2bf(acc[ct][reg]);
}

// ---------------------------------------------------------------------------
// Fused dispatch: blocks [0, BIN_BLOCKS) bin edges into bucket windows;
// remaining blocks run the bf16-MFMA GEMM with a 2-tile software pipeline
// (tile t+1's 16 loads issued before tile t's MFMA -> 16 KB/wave in flight).
// launch_bounds(256,2): allow up to 256 VGPR so the compiler does NOT
// serialize the 16 A-loads (round-5 VGPR=100 showed it did).
// ---------------------------------------------------------------------------
__global__ __launch_bounds__(256, 2) void gemm_bin_kernel(
    const float* __restrict__ x, const float* __restrict__ w,
    unsigned short* __restrict__ hiddenBf,
    const int* __restrict__ row, const int* __restrict__ col,
    const float* __restrict__ adj, int* __restrict__ gCursor,
    int2* __restrict__ edges)
{
    const int t = threadIdx.x;

    if (blockIdx.x < BIN_BLOCKS) {
        // ----- bin path -----
        __shared__ int cnt[N_BKT];
        __shared__ int cbase[N_BKT];
        __shared__ int cur[N_BKT];

        const int e0 = blockIdx.x * EPB;

        for (int i = t; i < N_BKT; i += 256) cnt[i] = 0;
        __syncthreads();

        for (int i = t; i < EPB; i += 256) {
            int e = e0 + i;
            if (e < N_EDGES) atomicAdd(&cnt[row[e] >> BKT_SHIFT], 1);
        }
        __syncthreads();

        for (int i = t; i < N_BKT; i += 256) {
            int c = cnt[i];
            cbase[i] = c ? atomicAdd(&gCursor[i * CUR_STRIDE], c) : 0;
            cur[i] = 0;
        }
        __syncthreads();

        for (int i = t; i < EPB; i += 256) {
            int e = e0 + i;
            if (e < N_EDGES) {
                int r = row[e];
                int b = r >> BKT_SHIFT;
                int off = cbase[b] + atomicAdd(&cur[b], 1);
                if (off < BKT_CAP) {  // capacity guard (never trips)
                    edges[b * BKT_CAP + off] =
                        make_int2(((r & (NODES_PER_B - 1)) << 17) | col[e],
                                  __float_as_int(adj[e]));
                }
            }
        }
        return;
    }

    // ----- gemm path -----
    __shared__ unsigned short wT[64][272];

    for (int i = 0; i < 64; ++i) {
        int idx = t + i * 256;
        int k = idx >> 6, n = idx & 63;
        wT[n][k] = f2bf(w[idx]);
    }
    __syncthreads();

    const int lane = t & 63;
    const int wid  = t >> 6;
    const int n16  = lane & 15;
    const int quad = lane >> 4;

    const int waveGid = (blockIdx.x - BIN_BLOCKS) * 4 + wid;
    const int t0 = waveGid * 2;
    if (t0 >= NUM_TILES) return;

    float4 lo[8], hi[8];
    short8 afrag[8];

    // prologue: issue all 16 loads of tile t0
    {
        const float* xrow = x + (size_t)(t0 * 16 + n16) * D_IN + quad * 8;
#pragma unroll
        for (int kk = 0; kk < 8; ++kk) {
            lo[kk] = *(const float4*)(xrow + kk * 32);
            hi[kk] = *(const float4*)(xrow + kk * 32 + 4);
        }
    }
    // convert tile t0 (forces one waitcnt), freeing lo/hi
#pragma unroll
    for (int kk = 0; kk < 8; ++kk) {
        short8 a;
        a[0] = (short)f2bf(lo[kk].x); a[1] = (short)f2bf(lo[kk].y);
        a[2] = (short)f2bf(lo[kk].z); a[3] = (short)f2bf(lo[kk].w);
        a[4] = (short)f2bf(hi[kk].x); a[5] = (short)f2bf(hi[kk].y);
        a[6] = (short)f2bf(hi[kk].z); a[7] = (short)f2bf(hi[kk].w);
        afrag[kk] = a;
    }

    const int t1 = t0 + 1;
    const bool have1 = t1 < NUM_TILES;
    if (have1) {
        // issue tile t1's 16 loads BEFORE tile t0's MFMA/store
        const float* xrow = x + (size_t)(t1 * 16 + n16) * D_IN + quad * 8;
#pragma unroll
        for (int kk = 0; kk < 8; ++kk) {
            lo[kk] = *(const float4*)(xrow + kk * 32);
            hi[kk] = *(const float4*)(xrow + kk * 32 + 4);
        }
    }

    mfma_store_tile(afrag, wT, hiddenBf, t0 * 16, n16, quad);

    if (have1) {
#pragma unroll
        for (int kk = 0; kk < 8; ++kk) {
            short8 a;
            a[0] = (short)f2bf(lo[kk].x); a[1] = (short)f2bf(lo[kk].y);
            a[2] = (short)f2bf(lo[kk].z); a[3] = (short)f2bf(lo[kk].w);
            a[4] = (short)f2bf(hi[kk].x); a[5] = (short)f2bf(hi[kk].y);
            a[6] = (short)f2bf(hi[kk].z); a[7] = (short)f2bf(hi[kk].w);
            afrag[kk] = a;
        }
        mfma_store_tile(afrag, wT, hiddenBf, t1 * 16, n16, quad);
    }
}

// ---------------------------------------------------------------------------
// Per-bucket CSR finalize, 512 threads (halved serial load depth vs 256).
// startdeg[node] = (gstart<<11) | deg.
// ---------------------------------------------------------------------------
__global__ __launch_bounds__(512) void csr_kernel(
    const int2* __restrict__ edges, const int* __restrict__ gCursor,
    int2* __restrict__ csr, unsigned int* __restrict__ startdeg)
{
    __shared__ int cnt[NODES_PER_B];
    __shared__ int cur[NODES_PER_B];

    const int b = blockIdx.x, t = threadIdx.x;
    if (t < NODES_PER_B) cnt[t] = 0;
    __syncthreads();

    const int base = b * BKT_CAP;
    int size = gCursor[b * CUR_STRIDE];
    if (size > BKT_CAP) size = BKT_CAP;

    for (int i = t; i < size; i += 512)
        atomicAdd(&cnt[(unsigned)edges[base + i].x >> 17], 1);
    __syncthreads();

    // Hillis-Steele inclusive scan over cnt[256] (barriers hit by all 512)
    int v = (t < NODES_PER_B) ? cnt[t] : 0;
    for (int off = 1; off < NODES_PER_B; off <<= 1) {
        int tmp = (t < NODES_PER_B && t >= off) ? cnt[t - off] : 0;
        __syncthreads();
        if (t < NODES_PER_B) cnt[t] += tmp;
        __syncthreads();
    }
    if (t < NODES_PER_B) {
        int gstart = base + cnt[t] - v;      // exclusive prefix + window base
        cur[t] = gstart;
        int node = b * NODES_PER_B + t;
        if (node < N_NODES)
            startdeg[node] = ((unsigned)gstart << 11) |
                             (unsigned)(v < 2047 ? v : 2047);
    }
    __syncthreads();

    for (int i = t; i < size; i += 512) {
        int2 rec = edges[base + i];
        int rl = (unsigned)rec.x >> 17;
        int pos = atomicAdd(&cur[rl], 1);
        csr[pos] = make_int2(rec.x & 0x1FFFF, rec.y);
    }
}

// ---------------------------------------------------------------------------
// Aggregate: one wave per node, records loaded once coalesced, broadcast via
// readlane. Gather loop unrolled x8 (avg deg ~10 -> one waitcnt group).
// ---------------------------------------------------------------------------
__global__ __launch_bounds__(256) void agg_kernel(
    const unsigned short* __restrict__ hiddenBf,
    const unsigned int* __restrict__ startdeg,
    const int2* __restrict__ csr, const float* __restrict__ prelu_a,
    float* __restrict__ out)
{
    const int wid  = threadIdx.x >> 6;
    const int lane = threadIdx.x & 63;
    const int node = blockIdx.x * 4 + wid;

    const unsigned int sd = startdeg[node];
    const int start = sd >> 11;
    const int deg   = sd & 2047;

    float acc = 0.f;
    for (int base = 0; base < deg; base += 64) {
        int take = deg - base;
        if (take > 64) take = 64;
        int2 rec = make_int2(0, 0);
        if (lane < take) rec = csr[start + base + lane];

        int j = 0;
        for (; j + 8 <= take; j += 8) {
            int   c[8]; float v[8]; float h[8];
#pragma unroll
            for (int u = 0; u < 8; ++u) {
                c[u] = __builtin_amdgcn_readlane(rec.x, j + u);
                v[u] = __int_as_float(__builtin_amdgcn_readlane(rec.y, j + u));
            }
#pragma unroll
            for (int u = 0; u < 8; ++u)
                h[u] = __uint_as_float(
                    (unsigned)hiddenBf[(size_t)c[u] * D_OUT + lane] << 16);
#pragma unroll
            for (int u = 0; u < 8; ++u) acc += v[u] * h[u];
        }
        for (; j < take; ++j) {
            int   c = __builtin_amdgcn_readlane(rec.x, j);
            float v = __int_as_float(__builtin_amdgcn_readlane(rec.y, j));
            float h = __uint_as_float(
                (unsigned)hiddenBf[(size_t)c * D_OUT + lane] << 16);
            acc += v * h;
        }
    }
    const float a = prelu_a[0];
    out[(size_t)node * D_OUT + lane] = acc > 0.f ? acc : a * acc;
}

// ---------------------------------------------------------------------------
extern "C" void kernel_launch(void* const* d_in, const int* in_sizes, int n_in,
                              void* d_out, int out_size, void* d_ws, size_t ws_size,
                              hipStream_t stream)
{
    const float* x       = (const float*)d_in[0];
    const float* w       = (const float*)d_in[1];
    const float* adj     = (const float*)d_in[2];
    const float* prelu_a = (const float*)d_in[3];
    const int*   row     = (const int*)d_in[4];
    const int*   col     = (const int*)d_in[5];
    float* out = (float*)d_out;

    // workspace layout (bytes)
    char* ws = (char*)d_ws;
    unsigned short* hiddenBf = (unsigned short*)(ws);        // 12,800,000
    int2*  edges    = (int2*)        (ws + 12800000);        //  9,609,216
    int2*  csr      = (int2*)        (ws + 22409216);        //  9,609,728 (+pad)
    unsigned int* startdeg = (unsigned int*)(ws + 32018944); //    400,384
    int*   gCursor  = (int*)         (ws + 32419328);        //     50,048 (391 x 128B)

    hipMemsetAsync(gCursor, 0, N_BKT * CUR_STRIDE * sizeof(int), stream);

    gemm_bin_kernel<<<BIN_BLOCKS + GEMM_BLOCKS, 256, 0, stream>>>(
        x, w, hiddenBf, row, col, adj, gCursor, edges);

    csr_kernel<<<N_BKT, 512, 0, stream>>>(edges, gCursor, csr, startdeg);

    agg_kernel<<<N_NODES / 4, 256, 0, stream>>>(hiddenBf, startdeg, csr, prelu_a, out);
}

// Round 3
// 244.540 us; speedup vs baseline: 1.0342x; 1.0339x over previous
//
#include <hip/hip_runtime.h>

#define N_NODES 100000
#define N_EDGES 1000000
#define D_IN    256
#define D_OUT   64

// bucket decomposition: 256 nodes per bucket
#define BKT_SHIFT   8
#define NODES_PER_B 256
#define N_BKT       391            // ceil(100000 / 256)
#define BKT_CAP     3072           // mean 2558, sigma ~51 -> +10 sigma slack
#define EPB         8192           // edges per binning block
#define BIN_BLOCKS  123            // ceil(1e6 / 8192)
#define GEMM_BLOCKS 782            // 3128 waves, 2 tiles/wave, 6250 tiles exact
#define NUM_TILES   6250           // 100000 / 16 exactly

// gCursor stride kept from round 1 (harmless; contention was disproven as
// the bottleneck but padding costs nothing).
#define CUR_STRIDE  32

typedef __attribute__((ext_vector_type(8))) short short8;
typedef __attribute__((ext_vector_type(4))) float f32x4;

__device__ __forceinline__ unsigned short f2bf(float f) {
    unsigned int u = __float_as_uint(f);
    u = (u + 0x7fffu + ((u >> 16) & 1u)) >> 16;
    return (unsigned short)u;
}

// MFMA + store for one 16-row tile; B read from LDS per use (keeps VGPRs for
// the A-load pipeline). wT pad = 272 shorts (544 B = 8 banks offset/row ->
// 4-way b128 aliasing instead of 8-way at 264).
__device__ __forceinline__ void mfma_store_tile(
    const short8 afrag[8], const unsigned short wT[64][272],
    unsigned short* __restrict__ hiddenBf, int r0, int n16, int quad)
{
    f32x4 acc[4] = {{0.f,0.f,0.f,0.f},{0.f,0.f,0.f,0.f},
                    {0.f,0.f,0.f,0.f},{0.f,0.f,0.f,0.f}};
#pragma unroll
    for (int ct = 0; ct < 4; ++ct) {
#pragma unroll
        for (int kk = 0; kk < 8; ++kk) {
            short8 b = *(const short8*)&wT[ct * 16 + n16][kk * 32 + quad * 8];
            acc[ct] = __builtin_amdgcn_mfma_f32_16x16x32_bf16(
                afrag[kk], b, acc[ct], 0, 0, 0);
        }
    }
    // C/D layout: col = lane&15, row = quad*4 + reg  [m89-verified]
#pragma unroll
    for (int ct = 0; ct < 4; ++ct)
#pragma unroll
        for (int reg = 0; reg < 4; ++reg)
            hiddenBf[(size_t)(r0 + quad * 4 + reg) * D_OUT + ct * 16 + n16]
                = f2bf(acc[ct][reg]);
}

// ---------------------------------------------------------------------------
// Fused dispatch: blocks [0, BIN_BLOCKS) bin edges into bucket windows;
// remaining blocks run the bf16-MFMA GEMM with a 2-tile software pipeline.
//
// Bin path (round 2): latency-bound before, not contention-bound (round-1
// padding null). Now fully unrolled register-batched loads: pass 1 issues
// all 32 row loads in flight; rreg[] kept across the barrier so pass 4
// never re-reads row; pass 4 batches col/adj 8-at-a-time. Exposed memory
// latencies per block: ~64 -> ~5.
// ---------------------------------------------------------------------------
__global__ __launch_bounds__(256, 2) void gemm_bin_kernel(
    const float* __restrict__ x, const float* __restrict__ w,
    unsigned short* __restrict__ hiddenBf,
    const int* __restrict__ row, const int* __restrict__ col,
    const float* __restrict__ adj, int* __restrict__ gCursor,
    int2* __restrict__ edges)
{
    const int t = threadIdx.x;

    if (blockIdx.x < BIN_BLOCKS) {
        // ----- bin path -----
        __shared__ int cnt[N_BKT];
        __shared__ int cbase[N_BKT];
        __shared__ int cur[N_BKT];

        const int e0 = blockIdx.x * EPB;

        for (int i = t; i < N_BKT; i += 256) cnt[i] = 0;
        __syncthreads();

        // pass 1: batch all 32 row loads (32 in flight -> one latency),
        // keep values in registers for pass 4.
        int rreg[32];
#pragma unroll
        for (int u = 0; u < 32; ++u) {
            int e = e0 + t + u * 256;
            rreg[u] = (e < N_EDGES) ? row[e] : -1;
        }
#pragma unroll
        for (int u = 0; u < 32; ++u)
            if (rreg[u] >= 0) atomicAdd(&cnt[rreg[u] >> BKT_SHIFT], 1);
        __syncthreads();

        for (int i = t; i < N_BKT; i += 256) {
            int c = cnt[i];
            cbase[i] = c ? atomicAdd(&gCursor[i * CUR_STRIDE], c) : 0;
            cur[i] = 0;
        }
        __syncthreads();

        // pass 4: chunks of 8; col/adj batched (16 loads in flight),
        // then 8 independent LDS-atomic + scatter-store pairs.
#pragma unroll
        for (int u0 = 0; u0 < 32; u0 += 8) {
            int   cc[8]; float vv[8];
#pragma unroll
            for (int u = 0; u < 8; ++u) {
                int e = e0 + t + (u0 + u) * 256;
                if (rreg[u0 + u] >= 0) { cc[u] = col[e]; vv[u] = adj[e]; }
                else                   { cc[u] = 0;      vv[u] = 0.f;    }
            }
#pragma unroll
            for (int u = 0; u < 8; ++u) {
                int r = rreg[u0 + u];
                if (r >= 0) {
                    int b = r >> BKT_SHIFT;
                    int off = cbase[b] + atomicAdd(&cur[b], 1);
                    if (off < BKT_CAP) {  // capacity guard (never trips)
                        edges[b * BKT_CAP + off] =
                            make_int2(((r & (NODES_PER_B - 1)) << 17) | cc[u],
                                      __float_as_int(vv[u]));
                    }
                }
            }
        }
        return;
    }

    // ----- gemm path -----
    __shared__ unsigned short wT[64][272];

    for (int i = 0; i < 64; ++i) {
        int idx = t + i * 256;
        int k = idx >> 6, n = idx & 63;
        wT[n][k] = f2bf(w[idx]);
    }
    __syncthreads();

    const int lane = t & 63;
    const int wid  = t >> 6;
    const int n16  = lane & 15;
    const int quad = lane >> 4;

    const int waveGid = (blockIdx.x - BIN_BLOCKS) * 4 + wid;
    const int t0 = waveGid * 2;
    if (t0 >= NUM_TILES) return;

    float4 lo[8], hi[8];
    short8 afrag[8];

    // prologue: issue all 16 loads of tile t0
    {
        const float* xrow = x + (size_t)(t0 * 16 + n16) * D_IN + quad * 8;
#pragma unroll
        for (int kk = 0; kk < 8; ++kk) {
            lo[kk] = *(const float4*)(xrow + kk * 32);
            hi[kk] = *(const float4*)(xrow + kk * 32 + 4);
        }
    }
    // convert tile t0 (forces one waitcnt), freeing lo/hi
#pragma unroll
    for (int kk = 0; kk < 8; ++kk) {
        short8 a;
        a[0] = (short)f2bf(lo[kk].x); a[1] = (short)f2bf(lo[kk].y);
        a[2] = (short)f2bf(lo[kk].z); a[3] = (short)f2bf(lo[kk].w);
        a[4] = (short)f2bf(hi[kk].x); a[5] = (short)f2bf(hi[kk].y);
        a[6] = (short)f2bf(hi[kk].z); a[7] = (short)f2bf(hi[kk].w);
        afrag[kk] = a;
    }

    const int t1 = t0 + 1;
    const bool have1 = t1 < NUM_TILES;
    if (have1) {
        // issue tile t1's 16 loads BEFORE tile t0's MFMA/store
        const float* xrow = x + (size_t)(t1 * 16 + n16) * D_IN + quad * 8;
#pragma unroll
        for (int kk = 0; kk < 8; ++kk) {
            lo[kk] = *(const float4*)(xrow + kk * 32);
            hi[kk] = *(const float4*)(xrow + kk * 32 + 4);
        }
    }

    mfma_store_tile(afrag, wT, hiddenBf, t0 * 16, n16, quad);

    if (have1) {
#pragma unroll
        for (int kk = 0; kk < 8; ++kk) {
            short8 a;
            a[0] = (short)f2bf(lo[kk].x); a[1] = (short)f2bf(lo[kk].y);
            a[2] = (short)f2bf(lo[kk].z); a[3] = (short)f2bf(lo[kk].w);
            a[4] = (short)f2bf(hi[kk].x); a[5] = (short)f2bf(hi[kk].y);
            a[6] = (short)f2bf(hi[kk].z); a[7] = (short)f2bf(hi[kk].w);
            afrag[kk] = a;
        }
        mfma_store_tile(afrag, wT, hiddenBf, t1 * 16, n16, quad);
    }
}

// ---------------------------------------------------------------------------
// Per-bucket CSR finalize, 512 threads (halved serial load depth vs 256).
// startdeg[node] = (gstart<<11) | deg.
// ---------------------------------------------------------------------------
__global__ __launch_bounds__(512) void csr_kernel(
    const int2* __restrict__ edges, const int* __restrict__ gCursor,
    int2* __restrict__ csr, unsigned int* __restrict__ startdeg)
{
    __shared__ int cnt[NODES_PER_B];
    __shared__ int cur[NODES_PER_B];

    const int b = blockIdx.x, t = threadIdx.x;
    if (t < NODES_PER_B) cnt[t] = 0;
    __syncthreads();

    const int base = b * BKT_CAP;
    int size = gCursor[b * CUR_STRIDE];
    if (size > BKT_CAP) size = BKT_CAP;

    for (int i = t; i < size; i += 512)
        atomicAdd(&cnt[(unsigned)edges[base + i].x >> 17], 1);
    __syncthreads();

    // Hillis-Steele inclusive scan over cnt[256] (barriers hit by all 512)
    int v = (t < NODES_PER_B) ? cnt[t] : 0;
    for (int off = 1; off < NODES_PER_B; off <<= 1) {
        int tmp = (t < NODES_PER_B && t >= off) ? cnt[t - off] : 0;
        __syncthreads();
        if (t < NODES_PER_B) cnt[t] += tmp;
        __syncthreads();
    }
    if (t < NODES_PER_B) {
        int gstart = base + cnt[t] - v;      // exclusive prefix + window base
        cur[t] = gstart;
        int node = b * NODES_PER_B + t;
        if (node < N_NODES)
            startdeg[node] = ((unsigned)gstart << 11) |
                             (unsigned)(v < 2047 ? v : 2047);
    }
    __syncthreads();

    for (int i = t; i < size; i += 512) {
        int2 rec = edges[base + i];
        int rl = (unsigned)rec.x >> 17;
        int pos = atomicAdd(&cur[rl], 1);
        csr[pos] = make_int2(rec.x & 0x1FFFF, rec.y);
    }
}

// ---------------------------------------------------------------------------
// Aggregate: one wave per node, records loaded once coalesced, broadcast via
// readlane. Gather loop unrolled x8 (avg deg ~10 -> one waitcnt group).
// ---------------------------------------------------------------------------
__global__ __launch_bounds__(256) void agg_kernel(
    const unsigned short* __restrict__ hiddenBf,
    const unsigned int* __restrict__ startdeg,
    const int2* __restrict__ csr, const float* __restrict__ prelu_a,
    float* __restrict__ out)
{
    const int wid  = threadIdx.x >> 6;
    const int lane = threadIdx.x & 63;
    const int node = blockIdx.x * 4 + wid;

    const unsigned int sd = startdeg[node];
    const int start = sd >> 11;
    const int deg   = sd & 2047;

    float acc = 0.f;
    for (int base = 0; base < deg; base += 64) {
        int take = deg - base;
        if (take > 64) take = 64;
        int2 rec = make_int2(0, 0);
        if (lane < take) rec = csr[start + base + lane];

        int j = 0;
        for (; j + 8 <= take; j += 8) {
            int   c[8]; float v[8]; float h[8];
#pragma unroll
            for (int u = 0; u < 8; ++u) {
                c[u] = __builtin_amdgcn_readlane(rec.x, j + u);
                v[u] = __int_as_float(__builtin_amdgcn_readlane(rec.y, j + u));
            }
#pragma unroll
            for (int u = 0; u < 8; ++u)
                h[u] = __uint_as_float(
                    (unsigned)hiddenBf[(size_t)c[u] * D_OUT + lane] << 16);
#pragma unroll
            for (int u = 0; u < 8; ++u) acc += v[u] * h[u];
        }
        for (; j < take; ++j) {
            int   c = __builtin_amdgcn_readlane(rec.x, j);
            float v = __int_as_float(__builtin_amdgcn_readlane(rec.y, j));
            float h = __uint_as_float(
                (unsigned)hiddenBf[(size_t)c * D_OUT + lane] << 16);
            acc += v * h;
        }
    }
    const float a = prelu_a[0];
    out[(size_t)node * D_OUT + lane] = acc > 0.f ? acc : a * acc;
}

// ---------------------------------------------------------------------------
extern "C" void kernel_launch(void* const* d_in, const int* in_sizes, int n_in,
                              void* d_out, int out_size, void* d_ws, size_t ws_size,
                              hipStream_t stream)
{
    const float* x       = (const float*)d_in[0];
    const float* w       = (const float*)d_in[1];
    const float* adj     = (const float*)d_in[2];
    const float* prelu_a = (const float*)d_in[3];
    const int*   row     = (const int*)d_in[4];
    const int*   col     = (const int*)d_in[5];
    float* out = (float*)d_out;

    // workspace layout (bytes)
    char* ws = (char*)d_ws;
    unsigned short* hiddenBf = (unsigned short*)(ws);        // 12,800,000
    int2*  edges    = (int2*)        (ws + 12800000);        //  9,609,216
    int2*  csr      = (int2*)        (ws + 22409216);        //  9,609,728 (+pad)
    unsigned int* startdeg = (unsigned int*)(ws + 32018944); //    400,384
    int*   gCursor  = (int*)         (ws + 32419328);        //     50,048 (391 x 128B)

    hipMemsetAsync(gCursor, 0, N_BKT * CUR_STRIDE * sizeof(int), stream);

    gemm_bin_kernel<<<BIN_BLOCKS + GEMM_BLOCKS, 256, 0, stream>>>(
        x, w, hiddenBf, row, col, adj, gCursor, edges);

    csr_kernel<<<N_BKT, 512, 0, stream>>>(edges, gCursor, csr, startdeg);

    agg_kernel<<<N_NODES / 4, 256, 0, stream>>>(hiddenBf, startdeg, csr, prelu_a, out);
}